// Round 8
// baseline (177.114 us; speedup 1.0000x reference)
//
#include <hip/hip_runtime.h>

#define H2C 450
#define WC 1242
#define HC 375
#define NPTS 4000000
#define NPIX (H2C * WC)   // 558900
#define TPB 256
#define FBLK 1024                  // fused kernel blocks: 4/CU co-resident (2x occupancy margin)
#define FTHREADS (FBLK * TPB)

// d_ws layout: [0..48) floats gmats: P_cam(16)|P_lid(16)|M(16); counter int at byte 192;
// winner int[NPIX] at byte 256.

__device__ __forceinline__ void mm4(float* o, const float* a, const float* b) {
    // o = a @ b ; k-sequential FMA chain. Bit-identical to rounds 1-7.
#pragma unroll
    for (int i = 0; i < 4; i++)
#pragma unroll
        for (int j = 0; j < 4; j++) {
            float t = a[i * 4 + 0] * b[0 * 4 + j];
            t = fmaf(a[i * 4 + 1], b[1 * 4 + j], t);
            t = fmaf(a[i * 4 + 2], b[2 * 4 + j], t);
            t = fmaf(a[i * 4 + 3], b[3 * 4 + j], t);
            o[i * 4 + j] = t;
        }
}

// Register-resident LAPACK sgetrf/getrs replica (r5-proven, bit-identical rounds 1-7).
__device__ void compute_mats(const float* K, const float* C, const float* L, float* out48) {
#pragma clang fp contract(off)
    float Pc[16], Pl[16], A[16], X[16], M[16];
    int piv[4];
    mm4(Pc, K, C);
    mm4(Pl, K, L);
#pragma unroll
    for (int k = 0; k < 16; k++) A[k] = Pl[k];

#pragma unroll
    for (int k = 0; k < 4; k++) {
        int p = k; float mx = fabsf(A[k * 4 + k]);
#pragma unroll
        for (int r = k + 1; r < 4; r++) {
            float v = fabsf(A[r * 4 + k]);
            if (v > mx) { mx = v; p = r; }
        }
        piv[k] = p;
#pragma unroll
        for (int r = k + 1; r < 4; r++) {
            bool sw = (p == r);
#pragma unroll
            for (int j = 0; j < 4; j++) {
                float tk = A[k * 4 + j], tr = A[r * 4 + j];
                A[k * 4 + j] = sw ? tr : tk;
                A[r * 4 + j] = sw ? tk : tr;
            }
        }
        float akk = A[k * 4 + k];
        if (fabsf(akk) >= 1.17549435e-38f) {
            float rr = 1.0f / akk;
#pragma unroll
            for (int r2 = k + 1; r2 < 4; r2++) A[r2 * 4 + k] = A[r2 * 4 + k] * rr;
        } else {
#pragma unroll
            for (int r2 = k + 1; r2 < 4; r2++) A[r2 * 4 + k] = A[r2 * 4 + k] / akk;
        }
#pragma unroll
        for (int r = k + 1; r < 4; r++) {
            float lik = A[r * 4 + k];
#pragma unroll
            for (int j = k + 1; j < 4; j++) A[r * 4 + j] = A[r * 4 + j] - lik * A[k * 4 + j];
        }
    }

#pragma unroll
    for (int k = 0; k < 16; k++) X[k] = 0.0f;
    X[0] = X[5] = X[10] = X[15] = 1.0f;
#pragma unroll
    for (int k = 0; k < 4; k++) {
        int p = piv[k];
#pragma unroll
        for (int r = k + 1; r < 4; r++) {
            bool sw = (p == r);
#pragma unroll
            for (int j = 0; j < 4; j++) {
                float tk = X[k * 4 + j], tr = X[r * 4 + j];
                X[k * 4 + j] = sw ? tr : tk;
                X[r * 4 + j] = sw ? tk : tr;
            }
        }
    }
#pragma unroll
    for (int j = 0; j < 4; j++) {
#pragma unroll
        for (int k = 0; k < 4; k++) {
            float xk = X[k * 4 + j];
#pragma unroll
            for (int r = k + 1; r < 4; r++) X[r * 4 + j] = X[r * 4 + j] - xk * A[r * 4 + k];
        }
#pragma unroll
        for (int k = 3; k >= 0; k--) {
            float xk = X[k * 4 + j] / A[k * 4 + k];
            X[k * 4 + j] = xk;
#pragma unroll
            for (int r = 0; r < k; r++) X[r * 4 + j] = X[r * 4 + j] - xk * A[r * 4 + k];
        }
    }
    mm4(M, Pc, X);
#pragma unroll
    for (int k = 0; k < 16; k++) { out48[k] = Pc[k]; out48[16 + k] = Pl[k]; out48[32 + k] = M[k]; }
}

// Node 1 (r5-proven): winner = -1 fill + register-LU mats on thread 0 + barrier-counter reset.
__global__ void init_mats_k(const float* __restrict__ K, const float* __restrict__ C,
                            const float* __restrict__ L, float* __restrict__ gmats,
                            int4* __restrict__ winner4, int* __restrict__ counter) {
    int i = blockIdx.x * blockDim.x + threadIdx.x;
    if (i < NPIX / 4) winner4[i] = make_int4(-1, -1, -1, -1);   // 558900 = 4*139725 exactly
    if (i == 0) compute_mats(K, C, L, gmats);
    if (i == 1) *counter = 0;   // manual-barrier counter, reset every call (graph-replay safe)
}

// Node 2: fused point-scatter + resolve, joined by a co-resident device spin barrier.
// 1024 blocks x 4 waves with VGPR<=128 -> 4 blocks/CU, all co-resident (2x margin).
__global__ void __launch_bounds__(TPB, 4)
fused_k(const float4* __restrict__ velo, const float* __restrict__ depth,
        const float* __restrict__ mats, int* __restrict__ winner, int* __restrict__ counter,
        float* __restrict__ img, float* __restrict__ noocc,
        float* __restrict__ org, float* __restrict__ fi) {
#pragma clang fp contract(off)
    __shared__ float srec[TPB * 7];
    const float* Pc = mats;
    const float* Pl = mats + 16;
    const float* M  = mats + 32;
    int tid = blockIdx.x * TPB + threadIdx.x;

    // ---- Phase B: per-point project + scatter (r5 point body verbatim); fi fill fused ----
    for (int i = tid; i < NPTS; i += FTHREADS) {
        fi[i] = 0.0f;
        float4 v = velo[i];
        float vp0 = fmaf(v.w, Pc[3],  fmaf(v.z, Pc[2],  fmaf(v.y, Pc[1], v.x * Pc[0])));
        float vp1 = fmaf(v.w, Pc[7],  fmaf(v.z, Pc[6],  fmaf(v.y, Pc[5], v.x * Pc[4])));
        float vz  = fmaf(v.w, Pc[11], fmaf(v.z, Pc[10], fmaf(v.y, Pc[9], v.x * Pc[8])));
        float vx = vp0 / vz;
        float vy = vp1 / vz;
        bool onimg = (v.x > 0.f) && (vx > 0.f) && (vx < (float)WC) && (vy > 0.f) && (vy < (float)HC);
        float nv0 = fmaf(v.w, Pl[3],  fmaf(v.z, Pl[2],  fmaf(v.y, Pl[1], v.x * Pl[0])));
        float nv1 = fmaf(v.w, Pl[7],  fmaf(v.z, Pl[6],  fmaf(v.y, Pl[5], v.x * Pl[4])));
        float nz  = fmaf(v.w, Pl[11], fmaf(v.z, Pl[10], fmaf(v.y, Pl[9], v.x * Pl[8])));
        float nx = nv0 / nz;
        float ny = nv1 / nz;
        float rx = rintf(nx);   // round half to even == jnp.round
        float ry = rintf(ny);
        // float-domain bounds checks reproduce numpy int32-cast outcomes (NaN/huge -> invalid)
        if (onimg && (nz > 0.f) && (rx >= 0.f) && (rx < (float)WC) && (ry >= 0.f) && (ry < (float)H2C)) {
            int px = (int)rx, py = (int)ry;
            atomicMax(&winner[py * WC + px], i);   // last-write-wins == max index wins
        }
    }

    // ---- Device-wide spin barrier (all FBLK blocks co-resident by construction) ----
    if (threadIdx.x == 0) {
        __hip_atomic_fetch_add(counter, 1, __ATOMIC_ACQ_REL, __HIP_MEMORY_SCOPE_AGENT);
        while (__hip_atomic_load(counter, __ATOMIC_ACQUIRE, __HIP_MEMORY_SCOPE_AGENT) < FBLK)
            __builtin_amdgcn_s_sleep(4);
    }
    __syncthreads();

    // ---- Phase C: resolve pixels (r5 resolve body verbatim); LDS-staged coalesced img ----
    for (int pb = blockIdx.x * TPB; pb < NPIX; pb += FTHREADS) {
        int p = pb + threadIdx.x;
        int valid = NPIX - pb; if (valid > TPB) valid = TPB;
        float o0 = 0.f, o1 = 0.f, o2 = 0.f, o3 = 0.f, o4 = 0.f, o5 = 0.f, o6 = 0.f;
        if (p < NPIX) {
            int wi = winner[p];
            if (wi >= 0) {
                float4 v = velo[wi];
                float vp0 = fmaf(v.w, Pc[3],  fmaf(v.z, Pc[2],  fmaf(v.y, Pc[1], v.x * Pc[0])));
                float vp1 = fmaf(v.w, Pc[7],  fmaf(v.z, Pc[6],  fmaf(v.y, Pc[5], v.x * Pc[4])));
                float vz  = fmaf(v.w, Pc[11], fmaf(v.z, Pc[10], fmaf(v.y, Pc[9], v.x * Pc[8])));
                float nv0 = fmaf(v.w, Pl[3],  fmaf(v.z, Pl[2],  fmaf(v.y, Pl[1], v.x * Pl[0])));
                float nv1 = fmaf(v.w, Pl[7],  fmaf(v.z, Pl[6],  fmaf(v.y, Pl[5], v.x * Pl[4])));
                float nz  = fmaf(v.w, Pl[11], fmaf(v.z, Pl[10], fmaf(v.y, Pl[9], v.x * Pl[8])));
                o0 = nv0 / nz; o1 = nv1 / nz; o2 = nz;
                o3 = vp0 / vz; o4 = vp1 / vz; o5 = vz;
                o6 = (float)wi;
                noocc[p] = 1.0f;
                org[p] = 1.0f;
                fi[wi] = 1.0f;   // winners unique per pixel -> no conflict
            } else {
                noocc[p] = 0.0f;
                org[p] = 0.0f;
                float d = depth[p];
                if (d > 0.0f) {
                    int y = p / WC, x = p - y * WC;
                    float fx = (float)x, fy = (float)y;
                    float p0 = fx * d, p1 = fy * d;
                    // np.einsum: plain left-to-right mul/add, no FMA (contract off above)
                    float pp0 = ((p0 * M[0] + p1 * M[1]) + d * M[2]) + M[3];
                    float pp1 = ((p0 * M[4] + p1 * M[5]) + d * M[6]) + M[7];
                    float pp2 = ((p0 * M[8] + p1 * M[9]) + d * M[10]) + M[11];
                    float zs = (pp2 != 0.0f) ? pp2 : 1.0f;
                    o0 = fx; o1 = fy; o2 = d;
                    o3 = pp0 / zs; o4 = pp1 / zs; o5 = pp2;
                    o6 = 0.0f;
                }
            }
        }
        float* r = srec + threadIdx.x * 7;
        r[0] = o0; r[1] = o1; r[2] = o2; r[3] = o3; r[4] = o4; r[5] = o5; r[6] = o6;
        __syncthreads();
        float* obase = img + (size_t)pb * 7;
        int nfl = valid * 7;
        for (int k = threadIdx.x; k < nfl; k += TPB) obase[k] = srec[k];
        __syncthreads();   // protect srec before next grid-stride iteration
    }
}

extern "C" void kernel_launch(void* const* d_in, const int* in_sizes, int n_in,
                              void* d_out, int out_size, void* d_ws, size_t ws_size,
                              hipStream_t stream) {
    const float* velo  = (const float*)d_in[0];
    const float* K     = (const float*)d_in[1];
    const float* C     = (const float*)d_in[2];
    const float* L     = (const float*)d_in[3];
    const float* depth = (const float*)d_in[4];

    float* out   = (float*)d_out;
    float* img   = out;                       // NPIX*7
    float* noocc = out + (size_t)NPIX * 7;    // NPIX
    float* org   = noocc + NPIX;              // NPIX
    float* fi    = org + NPIX;                // NPTS

    float* gmats   = (float*)d_ws;
    int*   counter = (int*)((char*)d_ws + 192);
    int*   winner  = (int*)((char*)d_ws + 256);

    init_mats_k<<<(NPIX / 4 + TPB - 1) / TPB, TPB, 0, stream>>>(K, C, L, gmats,
                                                                (int4*)winner, counter);

    fused_k<<<FBLK, TPB, 0, stream>>>((const float4*)velo, depth, gmats, winner, counter,
                                      img, noocc, org, fi);
}

// Round 9
// 28.904 us; speedup vs baseline: 6.1276x; 6.1276x over previous
//
#include <hip/hip_runtime.h>

#define H2C 450
#define WC 1242
#define HC 375
#define NPTS 4000000
#define NPIX (H2C * WC)   // 558900
#define TPB 256
#define HALF (NPTS / 2)   // 2,000,000

// d_ws layout: [0..48) floats gmats: P_cam(16)|P_lid(16)|M(16); winner int[NPIX] at byte 256.

__device__ __forceinline__ void mm4(float* o, const float* a, const float* b) {
    // o = a @ b ; k-sequential FMA chain. Bit-identical to rounds 1-8.
#pragma unroll
    for (int i = 0; i < 4; i++)
#pragma unroll
        for (int j = 0; j < 4; j++) {
            float t = a[i * 4 + 0] * b[0 * 4 + j];
            t = fmaf(a[i * 4 + 1], b[1 * 4 + j], t);
            t = fmaf(a[i * 4 + 2], b[2 * 4 + j], t);
            t = fmaf(a[i * 4 + 3], b[3 * 4 + j], t);
            o[i * 4 + j] = t;
        }
}

// Register-resident LAPACK sgetrf/getrs replica (r5-proven, bit-identical rounds 1-8).
__device__ void compute_mats(const float* K, const float* C, const float* L, float* out48) {
#pragma clang fp contract(off)
    float Pc[16], Pl[16], A[16], X[16], M[16];
    int piv[4];
    mm4(Pc, K, C);
    mm4(Pl, K, L);
#pragma unroll
    for (int k = 0; k < 16; k++) A[k] = Pl[k];

#pragma unroll
    for (int k = 0; k < 4; k++) {
        int p = k; float mx = fabsf(A[k * 4 + k]);
#pragma unroll
        for (int r = k + 1; r < 4; r++) {
            float v = fabsf(A[r * 4 + k]);
            if (v > mx) { mx = v; p = r; }
        }
        piv[k] = p;
#pragma unroll
        for (int r = k + 1; r < 4; r++) {
            bool sw = (p == r);
#pragma unroll
            for (int j = 0; j < 4; j++) {
                float tk = A[k * 4 + j], tr = A[r * 4 + j];
                A[k * 4 + j] = sw ? tr : tk;
                A[r * 4 + j] = sw ? tk : tr;
            }
        }
        float akk = A[k * 4 + k];
        if (fabsf(akk) >= 1.17549435e-38f) {
            float rr = 1.0f / akk;
#pragma unroll
            for (int r2 = k + 1; r2 < 4; r2++) A[r2 * 4 + k] = A[r2 * 4 + k] * rr;
        } else {
#pragma unroll
            for (int r2 = k + 1; r2 < 4; r2++) A[r2 * 4 + k] = A[r2 * 4 + k] / akk;
        }
#pragma unroll
        for (int r = k + 1; r < 4; r++) {
            float lik = A[r * 4 + k];
#pragma unroll
            for (int j = k + 1; j < 4; j++) A[r * 4 + j] = A[r * 4 + j] - lik * A[k * 4 + j];
        }
    }

#pragma unroll
    for (int k = 0; k < 16; k++) X[k] = 0.0f;
    X[0] = X[5] = X[10] = X[15] = 1.0f;
#pragma unroll
    for (int k = 0; k < 4; k++) {
        int p = piv[k];
#pragma unroll
        for (int r = k + 1; r < 4; r++) {
            bool sw = (p == r);
#pragma unroll
            for (int j = 0; j < 4; j++) {
                float tk = X[k * 4 + j], tr = X[r * 4 + j];
                X[k * 4 + j] = sw ? tr : tk;
                X[r * 4 + j] = sw ? tk : tr;
            }
        }
    }
#pragma unroll
    for (int j = 0; j < 4; j++) {
#pragma unroll
        for (int k = 0; k < 4; k++) {
            float xk = X[k * 4 + j];
#pragma unroll
            for (int r = k + 1; r < 4; r++) X[r * 4 + j] = X[r * 4 + j] - xk * A[r * 4 + k];
        }
#pragma unroll
        for (int k = 3; k >= 0; k--) {
            float xk = X[k * 4 + j] / A[k * 4 + k];
            X[k * 4 + j] = xk;
#pragma unroll
            for (int r = 0; r < k; r++) X[r * 4 + j] = X[r * 4 + j] - xk * A[r * 4 + k];
        }
    }
    mm4(M, Pc, X);
#pragma unroll
    for (int k = 0; k < 16; k++) { out48[k] = Pc[k]; out48[16 + k] = Pl[k]; out48[32 + k] = M[k]; }
}

// Node 1 (r5-proven): winner = -1 fill + register-LU mats on thread 0.
// LU's ~0.6us dependent chain hides under the 2.2MB fill done by the other waves.
__global__ void init_mats_k(const float* __restrict__ K, const float* __restrict__ C,
                            const float* __restrict__ L, float* __restrict__ gmats,
                            int4* __restrict__ winner4) {
    int i = blockIdx.x * blockDim.x + threadIdx.x;
    if (i < NPIX / 4) winner4[i] = make_int4(-1, -1, -1, -1);   // 558900 = 4*139725 exactly
    if (i == 0) compute_mats(K, C, L, gmats);
}

// Node 2: 2 points/thread (two independent float4 loads in flight -> MLP; half the blocks
// -> shorter dispatch ramp). mats from global via uniform s_load -> SGPR operands (r2/r5
// proven-fast path). fi zero-fill fused; resolve_k overwrites winners afterwards.
__device__ __forceinline__ void point_body(const float4* __restrict__ velo,
                                           const float* __restrict__ mats,
                                           int* __restrict__ winner,
                                           float* __restrict__ fi, int i) {
    fi[i] = 0.0f;
    float4 v = velo[i];
    const float* Pc = mats;
    const float* Pl = mats + 16;
    float vp0 = fmaf(v.w, Pc[3],  fmaf(v.z, Pc[2],  fmaf(v.y, Pc[1], v.x * Pc[0])));
    float vp1 = fmaf(v.w, Pc[7],  fmaf(v.z, Pc[6],  fmaf(v.y, Pc[5], v.x * Pc[4])));
    float vz  = fmaf(v.w, Pc[11], fmaf(v.z, Pc[10], fmaf(v.y, Pc[9], v.x * Pc[8])));
    float vx = vp0 / vz;
    float vy = vp1 / vz;
    bool onimg = (v.x > 0.f) && (vx > 0.f) && (vx < (float)WC) && (vy > 0.f) && (vy < (float)HC);
    float nv0 = fmaf(v.w, Pl[3],  fmaf(v.z, Pl[2],  fmaf(v.y, Pl[1], v.x * Pl[0])));
    float nv1 = fmaf(v.w, Pl[7],  fmaf(v.z, Pl[6],  fmaf(v.y, Pl[5], v.x * Pl[4])));
    float nz  = fmaf(v.w, Pl[11], fmaf(v.z, Pl[10], fmaf(v.y, Pl[9], v.x * Pl[8])));
    float nx = nv0 / nz;
    float ny = nv1 / nz;
    float rx = rintf(nx);   // round half to even == jnp.round
    float ry = rintf(ny);
    // float-domain bounds checks reproduce numpy int32-cast outcomes (NaN/huge -> invalid)
    if (onimg && (nz > 0.f) && (rx >= 0.f) && (rx < (float)WC) && (ry >= 0.f) && (ry < (float)H2C)) {
        int px = (int)rx, py = (int)ry;
        atomicMax(&winner[py * WC + px], i);   // last-write-wins == max index wins
    }
}

__global__ void __launch_bounds__(TPB)
point_k(const float4* __restrict__ velo, const float* __restrict__ mats,
        int* __restrict__ winner, float* __restrict__ fi) {
    int i = blockIdx.x * TPB + threadIdx.x;
    if (i < HALF) {
        point_body(velo, mats, winner, fi, i);
        point_body(velo, mats, winner, fi, i + HALF);
    }
}

__global__ void __launch_bounds__(TPB)
resolve_k(const float* __restrict__ depth, const float4* __restrict__ velo,
          const float* __restrict__ mats, const int* __restrict__ winner,
          float* __restrict__ img, float* __restrict__ noocc,
          float* __restrict__ org, float* __restrict__ fi) {
#pragma clang fp contract(off)
    __shared__ float srec[TPB * 7];
    int pb = blockIdx.x * TPB;
    int p = pb + threadIdx.x;
    int valid = NPIX - pb; if (valid > TPB) valid = TPB;
    float o0 = 0.f, o1 = 0.f, o2 = 0.f, o3 = 0.f, o4 = 0.f, o5 = 0.f, o6 = 0.f;
    if (p < NPIX) {
        int wi = winner[p];
        if (wi >= 0) {
            float4 v = velo[wi];
            const float* Pc = mats;
            const float* Pl = mats + 16;
            float vp0 = fmaf(v.w, Pc[3],  fmaf(v.z, Pc[2],  fmaf(v.y, Pc[1], v.x * Pc[0])));
            float vp1 = fmaf(v.w, Pc[7],  fmaf(v.z, Pc[6],  fmaf(v.y, Pc[5], v.x * Pc[4])));
            float vz  = fmaf(v.w, Pc[11], fmaf(v.z, Pc[10], fmaf(v.y, Pc[9], v.x * Pc[8])));
            float nv0 = fmaf(v.w, Pl[3],  fmaf(v.z, Pl[2],  fmaf(v.y, Pl[1], v.x * Pl[0])));
            float nv1 = fmaf(v.w, Pl[7],  fmaf(v.z, Pl[6],  fmaf(v.y, Pl[5], v.x * Pl[4])));
            float nz  = fmaf(v.w, Pl[11], fmaf(v.z, Pl[10], fmaf(v.y, Pl[9], v.x * Pl[8])));
            o0 = nv0 / nz; o1 = nv1 / nz; o2 = nz;
            o3 = vp0 / vz; o4 = vp1 / vz; o5 = vz;
            o6 = (float)wi;
            noocc[p] = 1.0f;
            org[p] = 1.0f;
            fi[wi] = 1.0f;   // winners unique per pixel -> no conflict
        } else {
            noocc[p] = 0.0f;
            org[p] = 0.0f;
            float d = depth[p];
            if (d > 0.0f) {
                int y = p / WC, x = p - y * WC;
                float fx = (float)x, fy = (float)y;
                const float* M = mats + 32;
                float p0 = fx * d, p1 = fy * d;
                // np.einsum: plain left-to-right mul/add, no FMA (contract off above)
                float pp0 = ((p0 * M[0] + p1 * M[1]) + d * M[2]) + M[3];
                float pp1 = ((p0 * M[4] + p1 * M[5]) + d * M[6]) + M[7];
                float pp2 = ((p0 * M[8] + p1 * M[9]) + d * M[10]) + M[11];
                float zs = (pp2 != 0.0f) ? pp2 : 1.0f;
                o0 = fx; o1 = fy; o2 = d;
                o3 = pp0 / zs; o4 = pp1 / zs; o5 = pp2;
                o6 = 0.0f;
            }
        }
    }
    // stage the 7-float record in LDS, then write back fully coalesced
    float* r = srec + threadIdx.x * 7;
    r[0] = o0; r[1] = o1; r[2] = o2; r[3] = o3; r[4] = o4; r[5] = o5; r[6] = o6;
    __syncthreads();
    float* obase = img + (size_t)pb * 7;
    int nfl = valid * 7;
    for (int k = threadIdx.x; k < nfl; k += TPB) obase[k] = srec[k];
}

extern "C" void kernel_launch(void* const* d_in, const int* in_sizes, int n_in,
                              void* d_out, int out_size, void* d_ws, size_t ws_size,
                              hipStream_t stream) {
    const float* velo  = (const float*)d_in[0];
    const float* K     = (const float*)d_in[1];
    const float* C     = (const float*)d_in[2];
    const float* L     = (const float*)d_in[3];
    const float* depth = (const float*)d_in[4];

    float* out   = (float*)d_out;
    float* img   = out;                       // NPIX*7
    float* noocc = out + (size_t)NPIX * 7;    // NPIX
    float* org   = noocc + NPIX;              // NPIX
    float* fi    = org + NPIX;                // NPTS

    float* gmats = (float*)d_ws;
    int* winner  = (int*)((char*)d_ws + 256);

    init_mats_k<<<(NPIX / 4 + TPB - 1) / TPB, TPB, 0, stream>>>(K, C, L, gmats, (int4*)winner);

    point_k<<<(HALF + TPB - 1) / TPB, TPB, 0, stream>>>((const float4*)velo, gmats, winner, fi);

    resolve_k<<<(NPIX + TPB - 1) / TPB, TPB, 0, stream>>>(depth, (const float4*)velo, gmats, winner,
                                                          img, noocc, org, fi);
}